// Round 17
// baseline (1972.352 us; speedup 1.0000x reference)
//
#include <hip/hip_runtime.h>

#define B_ROWS 8192
#define UNITS 512
#define NITER 25
#define INSZ 176
#define KPAD 128
#define GRAD_COLS 101

typedef __attribute__((ext_vector_type(8))) short short8;
typedef __attribute__((ext_vector_type(4))) float f32x4;
typedef __attribute__((ext_vector_type(8))) _Float16 half8;

__device__ __forceinline__ unsigned short f2h_bits(float f) {
  _Float16 h = (_Float16)f;
  return __builtin_bit_cast(unsigned short, h);
}
__device__ __forceinline__ float h2f_bits(unsigned short b) {
  return (float)__builtin_bit_cast(_Float16, b);
}
__device__ __forceinline__ float fast_tanh(float x) {
  float e = __expf(2.0f * x);
  return 1.0f - 2.0f / (e + 1.0f);
}

typedef __attribute__((address_space(3))) unsigned int lds_u32;
typedef __attribute__((address_space(1))) const unsigned int glb_u32;
__device__ __forceinline__ void gload16(const void* g, void* l) {
  __builtin_amdgcn_global_load_lds((glb_u32*)g, (lds_u32*)l, 16, 0, 0);
}

__device__ __forceinline__ f32x4 mf(short8 a, short8 b, f32x4 c) {
  return __builtin_amdgcn_mfma_f32_16x16x32_f16(
      __builtin_bit_cast(half8, a), __builtin_bit_cast(half8, b), c, 0, 0, 0);
}

struct GArgs {
  const unsigned short *A;            // activations plane, M x K (EPI != 4)
  const unsigned short *B;            // weights plane, N x K (n-major)
  int K;
  const float* bias;
  const unsigned short *Hh;           // EPI1: fwd activations
  unsigned short *Oh;                 // output plane (fp16)
  float* Og;                          // EPI2: grad out; EPI3: w_acc slice
  int iter;                           // EPI2: iter; EPI4: iteration i
  const float* W4p;                   // EPI3
  const float* xp;                    // EPI4
  float* woutp;                       // EPI4: writes col iter-1; EPI2-final: col 24
  const float* waccp;                 // EPI4: w_acc row (iter-1); EPI2-final: row 24
  const float* b4p;                   // EPI4 / EPI2-final
};

// ---------------------------------------------------------------------------
// Weight prep: fp16 planes, n-major layouts, zero-padded. Zeroes w_acc
// (required every call: EPI3 accumulates into it; harness replays).
// ---------------------------------------------------------------------------
__global__ __launch_bounds__(256)
void prep_kernel(const float* __restrict__ W0, const float* __restrict__ W1,
                 const float* __restrict__ W2, const float* __restrict__ W3,
                 unsigned short* TW0, unsigned short* TW1,
                 unsigned short* TW2, unsigned short* TW3,
                 unsigned short* CW0, unsigned short* CW1,
                 unsigned short* CW2, unsigned short* CW3,
                 float* w_acc)
{
  int id = blockIdx.x * 256 + threadIdx.x;
  if (id < NITER * B_ROWS) w_acc[id] = 0.0f;
  if (id < 512 * KPAD) {
    int n = id >> 7, k = id & (KPAD - 1);
    TW0[id] = f2h_bits((k < 101) ? W0[(size_t)k * 512 + n] : 0.0f);
    int n2 = id >> 9, k2 = id & 511;
    CW0[id] = f2h_bits((n2 < 101) ? W0[(size_t)n2 * 512 + k2] : 0.0f);
  }
  {
    int n = id >> 9, k = id & 511;
    TW1[id] = f2h_bits(W1[(size_t)k * 512 + n]);
    TW2[id] = f2h_bits(W2[(size_t)k * 512 + n]);
    TW3[id] = f2h_bits(W3[(size_t)k * 512 + n]);
    CW1[id] = f2h_bits(W1[id]);
    CW2[id] = f2h_bits(W2[id]);
    CW3[id] = f2h_bits(W3[id]);
  }
}

// ---------------------------------------------------------------------------
// Unified GEMM body: 64x128 tile, BK=32, 4 waves, 36KB LDS (3-buffer ring,
// 2-deep prefetch, counted vmcnt) -> 4 blocks/CU: 1024-block dispatches are
// EXACTLY resident (no degraded tail round — the round-12..16 slack).
// Swizzle for 64B rows: slot key (row>>1)&3 -> only parity 2-way bank
// aliasing, which is free (m136); write side stays linear for gload16.
// EPI 0: tanh(acc+bias) -> Oh
// EPI 1: acc*(1-h^2), h from Hh -> Oh
// EPI 2: grad store (bm=id grid, n<101); optional final w_out[:,24] write
// EPI 3: h=tanh(acc+bias); Oh=(1-h^2)*W4[n]; w-dot -> atomicAdd w_acc
// EPI 4: f0 with on-the-fly D built in LDS (full A, 4 K-slices) + B dbuf;
//        also writes w_out[:, iter-1].
// ---------------------------------------------------------------------------
template<int EPI>
__device__ __forceinline__ void gemm64(const GArgs g, short* smem, int id)
{
  const int t = threadIdx.x;
  const int w = t >> 6;
  const int lane = t & 63;
  const int l15 = lane & 15, l4 = lane >> 4;
  const int bm = (EPI == 2) ? id : ((id & 7) | ((id >> 5) << 3));
  const int bn = (EPI == 2) ? 0  : ((id >> 3) & 3);
  const int wm = (w >> 1) * 32, wn = (w & 1) * 64;
  const int K = g.K;
  const int NK = K >> 5;               // 32-wide K-steps
  f32x4 acc[2][4] = {};

  const int rr = t >> 2;               // 0..63 staging row
  const int sl = t & 3;                // 16B slot within 64B K-slice
  const int fr = (rr >> 1) & 3;        // swizzle key

  if constexpr (EPI == 4) {
    // build the 64x128 D tile in LDS: 4 K-slices of [64 rows][4 slots]
    const int i = g.iter;
    int b = bm * 64 + rr;
    float wv = (i > 0) ? (g.waccp[b] + g.b4p[0]) : 0.0f;
    if (i > 0 && sl == 0 && bn == 0)
      g.woutp[(size_t)b * NITER + (i - 1)] = wv;
    int cbase = (sl ^ fr) << 3;        // swizzled source col within K-slice
#pragma unroll
    for (int ks = 0; ks < 4; ++ks) {
      short8 vals;
#pragma unroll
      for (int j = 0; j < 8; ++j) {
        int col = ks * 32 + cbase + j;
        float val;
        if (col < 25 - i)       val = g.xp[(size_t)b * INSZ + i + col];
        else if (col < 24)      val = g.woutp[(size_t)b * NITER + (col - (25 - i))];
        else if (col == 24)     val = wv;
        else if (col < 100)     val = g.xp[(size_t)b * INSZ + 26 + 3 * i + (col - 25)];
        else if (col == 100)    val = (float)i;
        else                    val = 0.0f;
        vals[j] = (short)f2h_bits(val);
      }
      *(short8*)&smem[ks * 2048 + rr * 32 + sl * 8] = vals;
    }
  }

  // stage one BK=32 step: normal = A(1 gload) + B(2 gloads) -> ring buf;
  // EPI4 = B only (2 gloads) -> dbuf at smem+8192.
  auto stage = [&](int ks, int buf) {
    int kc = ks << 5;
    if constexpr (EPI != 4) {
      short* As = smem + buf * 6144;
      short* Bs = As + 2048;
      size_t ga = (size_t)(bm * 64 + rr) * K + kc + ((sl ^ fr) << 3);
      gload16(g.A + ga, &As[w * 512]);
#pragma unroll
      for (int q = 0; q < 2; ++q) {
        int r = q * 64 + rr;
        int f2 = (r >> 1) & 3;
        size_t gb = (size_t)(bn * 128 + r) * K + kc + ((sl ^ f2) << 3);
        gload16(g.B + gb, &Bs[q * 2048 + w * 512]);
      }
    } else {
      short* Bs = smem + 8192 + buf * 4096;
#pragma unroll
      for (int q = 0; q < 2; ++q) {
        int r = q * 64 + rr;
        int f2 = (r >> 1) & 3;
        size_t gb = (size_t)(bn * 128 + r) * K + kc + ((sl ^ f2) << 3);
        gload16(g.B + gb, &Bs[q * 2048 + w * 512]);
      }
    }
  };

  if constexpr (EPI == 4) {
    stage(0, 0);
  } else {
    stage(0, 0);
    stage(1, 1);
  }

  for (int ks = 0; ks < NK; ++ks) {
    if constexpr (EPI == 4) {
      if (ks + 1 < NK) {
        stage(ks + 1, (ks + 1) & 1);
        asm volatile("s_waitcnt vmcnt(2)" ::: "memory");
      } else {
        asm volatile("s_waitcnt vmcnt(0)" ::: "memory");
      }
    } else {
      if (ks + 2 < NK) {
        stage(ks + 2, (ks + 2) % 3);
        asm volatile("s_waitcnt vmcnt(6)" ::: "memory");  // stage(ks) done
      } else if (ks + 1 < NK) {
        asm volatile("s_waitcnt vmcnt(3)" ::: "memory");
      } else {
        asm volatile("s_waitcnt vmcnt(0)" ::: "memory");
      }
    }
    // leading lgkm drain (EPI4 ks==0: A-build ds_writes; else free)
    asm volatile("s_waitcnt lgkmcnt(0)" ::: "memory");
    __builtin_amdgcn_sched_barrier(0);
    __builtin_amdgcn_s_barrier();

    const short* As = (EPI == 4) ? (smem + ks * 2048) : (smem + (ks % 3) * 6144);
    const short* Bs = (EPI == 4) ? (smem + 8192 + (ks & 1) * 4096) : (As + 2048);

    short8 av[2], bh[4];
#pragma unroll
    for (int mi = 0; mi < 2; ++mi) {
      int row = wm + mi * 16 + l15;
      av[mi] = *(const short8*)&As[row * 32 + ((l4 ^ ((row >> 1) & 3)) << 3)];
    }
#pragma unroll
    for (int ni = 0; ni < 4; ++ni) {
      int row = wn + ni * 16 + l15;
      bh[ni] = *(const short8*)&Bs[row * 32 + ((l4 ^ ((row >> 1) & 3)) << 3)];
    }
    __builtin_amdgcn_s_setprio(1);
#pragma unroll
    for (int mi = 0; mi < 2; ++mi)
#pragma unroll
      for (int ni = 0; ni < 4; ++ni)
        acc[mi][ni] = mf(av[mi], bh[ni], acc[mi][ni]);
    __builtin_amdgcn_s_setprio(0);

    // reads of buf[ks] retired before any wave may overwrite it (ring dist 3)
    asm volatile("s_waitcnt lgkmcnt(0)" ::: "memory");
    __builtin_amdgcn_sched_barrier(0);
    __builtin_amdgcn_s_barrier();
  }

  const int gm0 = bm * 64 + wm;
  const int gn0 = bn * 128 + wn;
  float wp[2][4] = {};
#pragma unroll
  for (int mi = 0; mi < 2; ++mi) {
#pragma unroll
    for (int ni = 0; ni < 4; ++ni) {
      int n = gn0 + ni * 16 + l15;
#pragma unroll
      for (int r = 0; r < 4; ++r) {
        int m = gm0 + mi * 16 + l4 * 4 + r;
        float v = acc[mi][ni][r];
        if constexpr (EPI == 0 || EPI == 4) {
          float h = fast_tanh(v + g.bias[n]);
          g.Oh[(size_t)m * UNITS + n] = f2h_bits(h);
        } else if constexpr (EPI == 1) {
          size_t idx = (size_t)m * UNITS + n;
          float h = h2f_bits(g.Hh[idx]);
          g.Oh[idx] = f2h_bits(v * (1.0f - h * h));
        } else if constexpr (EPI == 2) {
          if (n < GRAD_COLS)
            g.Og[((size_t)m * NITER + g.iter) * GRAD_COLS + n] = v;
        } else {
          float h = fast_tanh(v + g.bias[n]);
          float w4 = g.W4p[n];
          g.Oh[(size_t)m * UNITS + n] = f2h_bits((1.0f - h * h) * w4);
          wp[mi][r] += h * w4;
        }
      }
    }
  }
  if constexpr (EPI == 3) {
#pragma unroll
    for (int mi = 0; mi < 2; ++mi)
#pragma unroll
      for (int r = 0; r < 4; ++r) {
        float v = wp[mi][r];
        v += __shfl_xor(v, 1); v += __shfl_xor(v, 2);
        v += __shfl_xor(v, 4); v += __shfl_xor(v, 8);
        if (l15 == 0) {
          int m = gm0 + mi * 16 + l4 * 4 + r;
          atomicAdd(&g.Og[m], v);
        }
      }
  }
  if constexpr (EPI == 2) {
    // final iteration only: w_out[:,24] = w_acc[24] + b4
    if (g.woutp && wn == 0 && l15 == 0) {
#pragma unroll
      for (int mi = 0; mi < 2; ++mi)
#pragma unroll
        for (int r = 0; r < 4; ++r) {
          int m = gm0 + mi * 16 + l4 * 4 + r;
          g.woutp[(size_t)m * NITER + 24] = g.waccp[m] + g.b4p[0];
        }
    }
  }
}

template<int EA, int EB>
__global__ __launch_bounds__(256, 4)
void paired_kernel(GArgs A, GArgs B, int nA) {
  __shared__ short smem[18432];        // 36KB -> 4 blocks/CU
  int id = blockIdx.x;
  if (id < nA) gemm64<EA>(A, smem, id);
  else         gemm64<EB>(B, smem, id - nA);
}

template<int E>
__global__ __launch_bounds__(256, 4)
void solo_kernel(GArgs A) {
  __shared__ short smem[18432];
  gemm64<E>(A, smem, blockIdx.x);
}

// ---------------------------------------------------------------------------
extern "C" void kernel_launch(void* const* d_in, const int* in_sizes, int n_in,
                              void* d_out, int out_size, void* d_ws, size_t ws_size,
                              hipStream_t stream) {
  const float* x  = (const float*)d_in[0];
  const float* W0 = (const float*)d_in[1];
  const float* b0 = (const float*)d_in[2];
  const float* W1 = (const float*)d_in[3];
  const float* b1 = (const float*)d_in[4];
  const float* W2 = (const float*)d_in[5];
  const float* b2 = (const float*)d_in[6];
  const float* W3 = (const float*)d_in[7];
  const float* b3 = (const float*)d_in[8];
  const float* W4 = (const float*)d_in[9];
  const float* b4 = (const float*)d_in[10];

  float* w_out    = (float*)d_out;                              // (8192, 25)
  float* grad_out = (float*)d_out + (size_t)B_ROWS * NITER;     // (8192, 25, 101)

  char* p = (char*)d_ws;
  auto alloc = [&](size_t elems) { unsigned short* r = (unsigned short*)p; p += elems * 2; return r; };

  unsigned short* TW0 = alloc(512 * KPAD);
  unsigned short* TW1 = alloc(512 * 512);
  unsigned short* TW2 = alloc(512 * 512);
  unsigned short* TW3 = alloc(512 * 512);
  unsigned short* CW0 = alloc(KPAD * 512);
  unsigned short* CW1 = alloc(512 * 512);
  unsigned short* CW2 = alloc(512 * 512);
  unsigned short* CW3 = alloc(512 * 512);
  float* w_acc = (float*)p; p += (size_t)NITER * B_ROWS * 4;

  const size_t SL = (size_t)B_ROWS * UNITS;
  unsigned short *H0[2], *H1[2], *H2[2], *U3[2];
  for (int par = 0; par < 2; ++par) {
    H0[par] = alloc(SL); H1[par] = alloc(SL);
    H2[par] = alloc(SL); U3[par] = alloc(SL);
  }
  unsigned short* Ub = alloc(SL);
  unsigned short* Uc = alloc(SL);

  prep_kernel<<<1024, 256, 0, stream>>>(W0, W1, W2, W3,
      TW0, TW1, TW2, TW3, CW0, CW1, CW2, CW3, w_acc);

  // prologue: forward chain for iteration 0 (parity 0); f0 builds D on the fly
  {
    GArgs f0 = {nullptr, TW0, KPAD, b0, nullptr, H0[0], nullptr, 0, nullptr,
                x, w_out, w_acc, b4};
    GArgs f1 = {H0[0], TW1, 512, b1, nullptr, H1[0], nullptr, 0, nullptr,
                nullptr, nullptr, nullptr, nullptr};
    GArgs f2 = {H1[0], TW2, 512, b2, nullptr, H2[0], nullptr, 0, nullptr,
                nullptr, nullptr, nullptr, nullptr};
    GArgs f3 = {H2[0], TW3, 512, b3, nullptr, U3[0], w_acc, 0, W4,
                nullptr, nullptr, nullptr, nullptr};
    solo_kernel<4><<<512, 256, 0, stream>>>(f0);
    solo_kernel<0><<<512, 256, 0, stream>>>(f1);
    solo_kernel<0><<<512, 256, 0, stream>>>(f2);
    solo_kernel<3><<<512, 256, 0, stream>>>(f3);
  }

  for (int i = 0; i < NITER; ++i) {
    int pp = i & 1, q = pp ^ 1;
    bool more = (i < NITER - 1);
    bool last = (i == NITER - 1);

    GArgs bw3 = {U3[pp], CW3, 512, nullptr, H2[pp], Ub, nullptr, 0, nullptr,
                 nullptr, nullptr, nullptr, nullptr};
    GArgs bw2 = {Ub,     CW2, 512, nullptr, H1[pp], Uc, nullptr, 0, nullptr,
                 nullptr, nullptr, nullptr, nullptr};
    GArgs bw1 = {Uc,     CW1, 512, nullptr, H0[pp], Ub, nullptr, 0, nullptr,
                 nullptr, nullptr, nullptr, nullptr};
    GArgs gr0 = {Ub,     CW0, 512, nullptr, nullptr, nullptr, grad_out, i, nullptr,
                 nullptr,
                 last ? w_out : nullptr,
                 last ? (w_acc + (size_t)24 * B_ROWS) : nullptr,
                 last ? b4 : nullptr};

    if (more) {
      // f-chain for iteration i+1; f0 builds D(i+1) on the fly, writes w_out[:,i]
      GArgs f0 = {nullptr, TW0, KPAD, b0, nullptr, H0[q], nullptr, i + 1, nullptr,
                  x, w_out, w_acc + (size_t)i * B_ROWS, b4};
      GArgs f1 = {H0[q], TW1, 512, b1, nullptr, H1[q], nullptr, 0, nullptr,
                  nullptr, nullptr, nullptr, nullptr};
      GArgs f2 = {H1[q], TW2, 512, b2, nullptr, H2[q], nullptr, 0, nullptr,
                  nullptr, nullptr, nullptr, nullptr};
      GArgs f3 = {H2[q], TW3, 512, b3, nullptr, U3[q],
                  w_acc + (size_t)(i + 1) * B_ROWS, 0, W4,
                  nullptr, nullptr, nullptr, nullptr};
      paired_kernel<1, 4><<<1024, 256, 0, stream>>>(bw3, f0, 512);
      paired_kernel<1, 0><<<1024, 256, 0, stream>>>(bw2, f1, 512);
      paired_kernel<1, 0><<<1024, 256, 0, stream>>>(bw1, f2, 512);
      paired_kernel<2, 3><<<640,  256, 0, stream>>>(gr0, f3, 128);
    } else {
      solo_kernel<1><<<512, 256, 0, stream>>>(bw3);
      solo_kernel<1><<<512, 256, 0, stream>>>(bw2);
      solo_kernel<1><<<512, 256, 0, stream>>>(bw1);
      solo_kernel<2><<<128, 256, 0, stream>>>(gr0);
    }
  }

  (void)in_sizes; (void)n_in; (void)out_size; (void)ws_size;
}

// Round 18
// 1722.338 us; speedup vs baseline: 1.1452x; 1.1452x over previous
//
#include <hip/hip_runtime.h>

#define B_ROWS 8192
#define UNITS 512
#define NITER 25
#define INSZ 176
#define KPAD 128
#define GRAD_COLS 101

typedef __attribute__((ext_vector_type(8))) short short8;
typedef __attribute__((ext_vector_type(4))) float f32x4;
typedef __attribute__((ext_vector_type(8))) _Float16 half8;

__device__ __forceinline__ unsigned short f2h_bits(float f) {
  _Float16 h = (_Float16)f;
  return __builtin_bit_cast(unsigned short, h);
}
__device__ __forceinline__ float h2f_bits(unsigned short b) {
  return (float)__builtin_bit_cast(_Float16, b);
}
__device__ __forceinline__ float fast_tanh(float x) {
  float e = __expf(2.0f * x);
  return 1.0f - 2.0f / (e + 1.0f);
}

typedef __attribute__((address_space(3))) unsigned int lds_u32;
typedef __attribute__((address_space(1))) const unsigned int glb_u32;
__device__ __forceinline__ void gload16(const void* g, void* l) {
  __builtin_amdgcn_global_load_lds((glb_u32*)g, (lds_u32*)l, 16, 0, 0);
}

__device__ __forceinline__ f32x4 mf(short8 a, short8 b, f32x4 c) {
  return __builtin_amdgcn_mfma_f32_16x16x32_f16(
      __builtin_bit_cast(half8, a), __builtin_bit_cast(half8, b), c, 0, 0, 0);
}

struct GArgs {
  const unsigned short *A;            // activations plane, M x K (EPI != 4)
  const unsigned short *B;            // weights plane, N x K (n-major)
  int K;
  const float* bias;
  const unsigned short *Hh;           // EPI1: fwd activations
  unsigned short *Oh;                 // output plane (fp16)
  float* Og;                          // EPI2: grad out; EPI3: w_acc slice
  int iter;                           // EPI2: iter; EPI4: iteration i
  const float* W4p;                   // EPI3
  const float* xp;                    // EPI4
  float* woutp;                       // EPI4: writes col iter-1; EPI2-final: col 24
  const float* waccp;                 // EPI4: w_acc row (iter-1); EPI2-final: row 24
  const float* b4p;                   // EPI4 / EPI2-final
};

// ---------------------------------------------------------------------------
// Weight prep: fp16 planes, n-major layouts, zero-padded. Zeroes w_acc
// (required every call: EPI3 accumulates into it; harness replays).
// ---------------------------------------------------------------------------
__global__ __launch_bounds__(256)
void prep_kernel(const float* __restrict__ W0, const float* __restrict__ W1,
                 const float* __restrict__ W2, const float* __restrict__ W3,
                 unsigned short* TW0, unsigned short* TW1,
                 unsigned short* TW2, unsigned short* TW3,
                 unsigned short* CW0, unsigned short* CW1,
                 unsigned short* CW2, unsigned short* CW3,
                 float* w_acc)
{
  int id = blockIdx.x * 256 + threadIdx.x;
  if (id < NITER * B_ROWS) w_acc[id] = 0.0f;
  if (id < 512 * KPAD) {
    int n = id >> 7, k = id & (KPAD - 1);
    TW0[id] = f2h_bits((k < 101) ? W0[(size_t)k * 512 + n] : 0.0f);
    int n2 = id >> 9, k2 = id & 511;
    CW0[id] = f2h_bits((n2 < 101) ? W0[(size_t)n2 * 512 + k2] : 0.0f);
  }
  {
    int n = id >> 9, k = id & 511;
    TW1[id] = f2h_bits(W1[(size_t)k * 512 + n]);
    TW2[id] = f2h_bits(W2[(size_t)k * 512 + n]);
    TW3[id] = f2h_bits(W3[(size_t)k * 512 + n]);
    CW1[id] = f2h_bits(W1[id]);
    CW2[id] = f2h_bits(W2[id]);
    CW3[id] = f2h_bits(W3[id]);
  }
}

// ---------------------------------------------------------------------------
// Unified GEMM body: 64x128 tile, BK=64, 4 waves, 48KB LDS, 3 blocks/CU.
// Counted-vmcnt 2-barrier pipeline (replay-verified rounds 5-12).
// EPI 0: tanh(acc+bias) -> Oh
// EPI 1: acc*(1-h^2), h from Hh -> Oh
// EPI 2: grad store (bm=id grid, n<101); optional final w_out[:,24] write
// EPI 3: h=tanh(acc+bias); Oh=(1-h^2)*W4[n]; w-dot -> atomicAdd w_acc
// EPI 4: f0 with on-the-fly D built in LDS from x/w_out/w_acc; also writes
//        w_out[:, iter-1] (bn==0, ss==0 lanes).
// ---------------------------------------------------------------------------
template<int EPI>
__device__ __forceinline__ void gemm64(const GArgs g, short* smem, int id)
{
  const int t = threadIdx.x;
  const int w = t >> 6;
  const int lane = t & 63;
  const int l15 = lane & 15, l4 = lane >> 4;
  const int bm = (EPI == 2) ? id : ((id & 7) | ((id >> 5) << 3));
  const int bn = (EPI == 2) ? 0  : ((id >> 3) & 3);
  const int wm = (w >> 1) * 32, wn = (w & 1) * 64;
  const int K = g.K;
  const int NK = K >> 6;
  f32x4 acc[2][4] = {};

  const int sr = t >> 3;   // 0..31
  const int ss = t & 7;

  if constexpr (EPI == 4) {
    // build the 64x128 D tile in LDS (two 4096-short K-halves at smem[0..8192))
    const int i = g.iter;
#pragma unroll
    for (int q = 0; q < 2; ++q) {
      int r = q * 32 + sr;
      int b = bm * 64 + r;
      float wv = (i > 0) ? (g.waccp[b] + g.b4p[0]) : 0.0f;
      if (i > 0 && ss == 0 && bn == 0)
        g.woutp[(size_t)b * NITER + (i - 1)] = wv;
      int cc = (ss ^ (r & 7)) << 3;            // global col base for this slot
#pragma unroll
      for (int half = 0; half < 2; ++half) {
        short8 vals;
#pragma unroll
        for (int j = 0; j < 8; ++j) {
          int col = half * 64 + cc + j;
          float val;
          if (col < 25 - i)       val = g.xp[(size_t)b * INSZ + i + col];
          else if (col < 24)      val = g.woutp[(size_t)b * NITER + (col - (25 - i))];
          else if (col == 24)     val = wv;
          else if (col < 100)     val = g.xp[(size_t)b * INSZ + 26 + 3 * i + (col - 25)];
          else if (col == 100)    val = (float)i;
          else                    val = 0.0f;
          vals[j] = (short)f2h_bits(val);
        }
        *(short8*)&smem[half * 4096 + r * 64 + ss * 8] = vals;
      }
    }
  }

  // stage: EPI4 -> B only (4 gloads, bufs at smem+8192); else A+B (6 gloads)
  auto stage = [&](int ks, int buf) {
    int kc = ks << 6;
    if constexpr (EPI != 4) {
      short* As = smem + buf * 12288;
      short* Bs = As + 4096;
#pragma unroll
      for (int q = 0; q < 2; ++q) {                  // A: 64 rows
        int r = q * 32 + sr;
        int c = ss ^ (r & 7);
        size_t ga = (size_t)(bm * 64 + r) * K + kc + c * 8;
        gload16(g.A + ga, &As[q * 2048 + w * 512]);
      }
#pragma unroll
      for (int q = 0; q < 4; ++q) {                  // B: 128 rows
        int r = q * 32 + sr;
        int c = ss ^ (r & 7);
        size_t gb = (size_t)(bn * 128 + r) * K + kc + c * 8;
        gload16(g.B + gb, &Bs[q * 2048 + w * 512]);
      }
    } else {
      short* Bs = smem + 8192 + buf * 8192;
#pragma unroll
      for (int q = 0; q < 4; ++q) {
        int r = q * 32 + sr;
        int c = ss ^ (r & 7);
        size_t gb = (size_t)(bn * 128 + r) * K + kc + c * 8;
        gload16(g.B + gb, &Bs[q * 2048 + w * 512]);
      }
    }
  };

  stage(0, 0);
  for (int ks = 0; ks < NK; ++ks) {
    if (ks + 1 < NK) {
      stage(ks + 1, (ks + 1) & 1);
      if constexpr (EPI == 4) asm volatile("s_waitcnt vmcnt(4)" ::: "memory");
      else                    asm volatile("s_waitcnt vmcnt(6)" ::: "memory");
    } else {
      asm volatile("s_waitcnt vmcnt(0)" ::: "memory");
    }
    // leading lgkm drain: EPI4 ks==0 needs A-build ds_writes visible;
    // otherwise free (trailing edge already drained to 0).
    asm volatile("s_waitcnt lgkmcnt(0)" ::: "memory");
    __builtin_amdgcn_sched_barrier(0);
    __builtin_amdgcn_s_barrier();

    const short* As = (EPI == 4) ? (smem + ks * 4096) : (smem + (ks & 1) * 12288);
    const short* Bs = (EPI == 4) ? (smem + 8192 + (ks & 1) * 8192) : (As + 4096);
#pragma unroll
    for (int kk = 0; kk < 2; ++kk) {
      short8 av[2], bh[4];
#pragma unroll
      for (int mi = 0; mi < 2; ++mi) {
        int row = wm + mi * 16 + l15;
        av[mi] = *(const short8*)&As[row * 64 + (((kk * 4 + l4) ^ (row & 7)) << 3)];
      }
#pragma unroll
      for (int ni = 0; ni < 4; ++ni) {
        int row = wn + ni * 16 + l15;
        bh[ni] = *(const short8*)&Bs[row * 64 + (((kk * 4 + l4) ^ (row & 7)) << 3)];
      }
#pragma unroll
      for (int mi = 0; mi < 2; ++mi)
#pragma unroll
        for (int ni = 0; ni < 4; ++ni)
          acc[mi][ni] = mf(av[mi], bh[ni], acc[mi][ni]);
    }
    asm volatile("s_waitcnt lgkmcnt(0)" ::: "memory");
    __builtin_amdgcn_sched_barrier(0);
    __builtin_amdgcn_s_barrier();
  }

  const int gm0 = bm * 64 + wm;
  const int gn0 = bn * 128 + wn;
  float wp[2][4] = {};
#pragma unroll
  for (int mi = 0; mi < 2; ++mi) {
#pragma unroll
    for (int ni = 0; ni < 4; ++ni) {
      int n = gn0 + ni * 16 + l15;
#pragma unroll
      for (int r = 0; r < 4; ++r) {
        int m = gm0 + mi * 16 + l4 * 4 + r;
        float v = acc[mi][ni][r];
        if constexpr (EPI == 0 || EPI == 4) {
          float h = fast_tanh(v + g.bias[n]);
          g.Oh[(size_t)m * UNITS + n] = f2h_bits(h);
        } else if constexpr (EPI == 1) {
          size_t idx = (size_t)m * UNITS + n;
          float h = h2f_bits(g.Hh[idx]);
          g.Oh[idx] = f2h_bits(v * (1.0f - h * h));
        } else if constexpr (EPI == 2) {
          if (n < GRAD_COLS)
            g.Og[((size_t)m * NITER + g.iter) * GRAD_COLS + n] = v;
        } else {
          float h = fast_tanh(v + g.bias[n]);
          float w4 = g.W4p[n];
          g.Oh[(size_t)m * UNITS + n] = f2h_bits((1.0f - h * h) * w4);
          wp[mi][r] += h * w4;
        }
      }
    }
  }
  if constexpr (EPI == 3) {
#pragma unroll
    for (int mi = 0; mi < 2; ++mi)
#pragma unroll
      for (int r = 0; r < 4; ++r) {
        float v = wp[mi][r];
        v += __shfl_xor(v, 1); v += __shfl_xor(v, 2);
        v += __shfl_xor(v, 4); v += __shfl_xor(v, 8);
        if (l15 == 0) {
          int m = gm0 + mi * 16 + l4 * 4 + r;
          atomicAdd(&g.Og[m], v);
        }
      }
  }
  if constexpr (EPI == 2) {
    // final iteration only: w_out[:,24] = w_acc[24] + b4
    if (g.woutp && wn == 0 && l15 == 0) {
#pragma unroll
      for (int mi = 0; mi < 2; ++mi)
#pragma unroll
        for (int r = 0; r < 4; ++r) {
          int m = gm0 + mi * 16 + l4 * 4 + r;
          g.woutp[(size_t)m * NITER + 24] = g.waccp[m] + g.b4p[0];
        }
    }
  }
}

template<int EA, int EB>
__global__ __launch_bounds__(256, 3)
void paired_kernel(GArgs A, GArgs B, int nA) {
  __shared__ short smem[24576];        // 48KB -> 3 blocks/CU
  int id = blockIdx.x;
  if (id < nA) gemm64<EA>(A, smem, id);
  else         gemm64<EB>(B, smem, id - nA);
}

template<int E>
__global__ __launch_bounds__(256, 3)
void solo_kernel(GArgs A) {
  __shared__ short smem[24576];
  gemm64<E>(A, smem, blockIdx.x);
}

// ---------------------------------------------------------------------------
extern "C" void kernel_launch(void* const* d_in, const int* in_sizes, int n_in,
                              void* d_out, int out_size, void* d_ws, size_t ws_size,
                              hipStream_t stream) {
  const float* x  = (const float*)d_in[0];
  const float* W0 = (const float*)d_in[1];
  const float* b0 = (const float*)d_in[2];
  const float* W1 = (const float*)d_in[3];
  const float* b1 = (const float*)d_in[4];
  const float* W2 = (const float*)d_in[5];
  const float* b2 = (const float*)d_in[6];
  const float* W3 = (const float*)d_in[7];
  const float* b3 = (const float*)d_in[8];
  const float* W4 = (const float*)d_in[9];
  const float* b4 = (const float*)d_in[10];

  float* w_out    = (float*)d_out;                              // (8192, 25)
  float* grad_out = (float*)d_out + (size_t)B_ROWS * NITER;     // (8192, 25, 101)

  char* p = (char*)d_ws;
  auto alloc = [&](size_t elems) { unsigned short* r = (unsigned short*)p; p += elems * 2; return r; };

  unsigned short* TW0 = alloc(512 * KPAD);
  unsigned short* TW1 = alloc(512 * 512);
  unsigned short* TW2 = alloc(512 * 512);
  unsigned short* TW3 = alloc(512 * 512);
  unsigned short* CW0 = alloc(KPAD * 512);
  unsigned short* CW1 = alloc(512 * 512);
  unsigned short* CW2 = alloc(512 * 512);
  unsigned short* CW3 = alloc(512 * 512);
  float* w_acc = (float*)p; p += (size_t)NITER * B_ROWS * 4;

  const size_t SL = (size_t)B_ROWS * UNITS;
  unsigned short *H0[2], *H1[2], *H2[2], *U3[2];
  for (int par = 0; par < 2; ++par) {
    H0[par] = alloc(SL); H1[par] = alloc(SL);
    H2[par] = alloc(SL); U3[par] = alloc(SL);
  }
  unsigned short* Ub = alloc(SL);
  unsigned short* Uc = alloc(SL);

  prep_kernel<<<1024, 256, 0, stream>>>(W0, W1, W2, W3,
      TW0, TW1, TW2, TW3, CW0, CW1, CW2, CW3, w_acc);

  // prologue: forward chain for iteration 0 (parity 0); f0 builds D on the fly
  {
    GArgs f0 = {nullptr, TW0, KPAD, b0, nullptr, H0[0], nullptr, 0, nullptr,
                x, w_out, w_acc, b4};
    GArgs f1 = {H0[0], TW1, 512, b1, nullptr, H1[0], nullptr, 0, nullptr,
                nullptr, nullptr, nullptr, nullptr};
    GArgs f2 = {H1[0], TW2, 512, b2, nullptr, H2[0], nullptr, 0, nullptr,
                nullptr, nullptr, nullptr, nullptr};
    GArgs f3 = {H2[0], TW3, 512, b3, nullptr, U3[0], w_acc, 0, W4,
                nullptr, nullptr, nullptr, nullptr};
    solo_kernel<4><<<512, 256, 0, stream>>>(f0);
    solo_kernel<0><<<512, 256, 0, stream>>>(f1);
    solo_kernel<0><<<512, 256, 0, stream>>>(f2);
    solo_kernel<3><<<512, 256, 0, stream>>>(f3);
  }

  for (int i = 0; i < NITER; ++i) {
    int pp = i & 1, q = pp ^ 1;
    bool more = (i < NITER - 1);
    bool last = (i == NITER - 1);

    GArgs bw3 = {U3[pp], CW3, 512, nullptr, H2[pp], Ub, nullptr, 0, nullptr,
                 nullptr, nullptr, nullptr, nullptr};
    GArgs bw2 = {Ub,     CW2, 512, nullptr, H1[pp], Uc, nullptr, 0, nullptr,
                 nullptr, nullptr, nullptr, nullptr};
    GArgs bw1 = {Uc,     CW1, 512, nullptr, H0[pp], Ub, nullptr, 0, nullptr,
                 nullptr, nullptr, nullptr, nullptr};
    GArgs gr0 = {Ub,     CW0, 512, nullptr, nullptr, nullptr, grad_out, i, nullptr,
                 nullptr,
                 last ? w_out : nullptr,
                 last ? (w_acc + (size_t)24 * B_ROWS) : nullptr,
                 last ? b4 : nullptr};

    if (more) {
      // f-chain for iteration i+1; f0 builds D(i+1) on the fly, writes w_out[:,i]
      GArgs f0 = {nullptr, TW0, KPAD, b0, nullptr, H0[q], nullptr, i + 1, nullptr,
                  x, w_out, w_acc + (size_t)i * B_ROWS, b4};
      GArgs f1 = {H0[q], TW1, 512, b1, nullptr, H1[q], nullptr, 0, nullptr,
                  nullptr, nullptr, nullptr, nullptr};
      GArgs f2 = {H1[q], TW2, 512, b2, nullptr, H2[q], nullptr, 0, nullptr,
                  nullptr, nullptr, nullptr, nullptr};
      GArgs f3 = {H2[q], TW3, 512, b3, nullptr, U3[q],
                  w_acc + (size_t)(i + 1) * B_ROWS, 0, W4,
                  nullptr, nullptr, nullptr, nullptr};
      paired_kernel<1, 4><<<1024, 256, 0, stream>>>(bw3, f0, 512);
      paired_kernel<1, 0><<<1024, 256, 0, stream>>>(bw2, f1, 512);
      paired_kernel<1, 0><<<1024, 256, 0, stream>>>(bw1, f2, 512);
      paired_kernel<2, 3><<<640,  256, 0, stream>>>(gr0, f3, 128);
    } else {
      solo_kernel<1><<<512, 256, 0, stream>>>(bw3);
      solo_kernel<1><<<512, 256, 0, stream>>>(bw2);
      solo_kernel<1><<<512, 256, 0, stream>>>(bw1);
      solo_kernel<2><<<128, 256, 0, stream>>>(gr0);
    }
  }

  (void)in_sizes; (void)n_in; (void)out_size; (void)ws_size;
}